// Round 4
// baseline (8991.928 us; speedup 1.0000x reference)
//
#include <hip/hip_runtime.h>
#include <math.h>

#define T_ 200

// ---------------- xg GEMM for one C-timestep chunk, one direction, with the
// embedding gather (char_table[ci] * feat_table[fi]) fused into the A-tile load.
// C[rows x 1024] = emb_chunk[rows x 256] @ Wih^T + bias, rows = C*256.
// tiles: 64(M) x 128(N) x 32(K); 256 threads; micro-tile 4x8.
// Chunk local row r holds timestep t = t0 + sgn*r (sgn=+1 fwd, -1 bwd).
__global__ __launch_bounds__(256) void xg_gemm(
    const int* __restrict__ bin, const int* __restrict__ bfe,
    const float* __restrict__ ctab, const float* __restrict__ ftab,
    const float* __restrict__ wih, const float* __restrict__ bias,
    float* __restrict__ xgslot, int t0, int sgn) {
  __shared__ float As[32][68];    // transposed A tile [k][m]
  __shared__ float Bs[32][132];   // transposed B tile [k][n]
  const int tid = threadIdx.x;
  const int m0 = blockIdx.x * 64;
  const int n0 = blockIdx.y * 128;

  const int mm = tid & 15;
  const int nn = tid >> 4;

  float acc[2][4][4];
  #pragma unroll
  for (int q = 0; q < 2; ++q)
    #pragma unroll
    for (int i = 0; i < 4; ++i)
      #pragma unroll
      for (int j2 = 0; j2 < 4; ++j2) acc[q][i][j2] = 0.f;

  const int ra = tid & 63, ka = tid >> 6;    // A stage: row, 8-k group
  const int rb = tid & 127, kb = tid >> 7;   // B stage: row(n), 16-k group

  // fused gather: indices for this thread's A row (fixed across K-loop)
  const int mrow = m0 + ra;
  const int rloc = mrow >> 8;          // local timestep within chunk
  const int bcol = mrow & 255;         // batch index
  const int t = t0 + sgn * rloc;
  const float* cr = ctab + ((size_t)bin[bcol * T_ + t] << 8);
  const float* fr = ftab + ((size_t)bfe[bcol * T_ + t] << 8);

  for (int ks = 0; ks < 256; ks += 32) {
    {
      const float* c0p = cr + ks + ka * 8;
      const float* f0p = fr + ks + ka * 8;
      float4 c0 = *(const float4*)(c0p);
      float4 c1 = *(const float4*)(c0p + 4);
      float4 f0 = *(const float4*)(f0p);
      float4 f1 = *(const float4*)(f0p + 4);
      int kk = ka * 8;
      As[kk + 0][ra] = c0.x * f0.x; As[kk + 1][ra] = c0.y * f0.y;
      As[kk + 2][ra] = c0.z * f0.z; As[kk + 3][ra] = c0.w * f0.w;
      As[kk + 4][ra] = c1.x * f1.x; As[kk + 5][ra] = c1.y * f1.y;
      As[kk + 6][ra] = c1.z * f1.z; As[kk + 7][ra] = c1.w * f1.w;
    }
    {
      const float* src = wih + (size_t)(n0 + rb) * 256 + ks + kb * 16;
      float4 v0 = *(const float4*)(src);
      float4 v1 = *(const float4*)(src + 4);
      float4 v2 = *(const float4*)(src + 8);
      float4 v3 = *(const float4*)(src + 12);
      int kk = kb * 16;
      Bs[kk + 0][rb] = v0.x; Bs[kk + 1][rb] = v0.y; Bs[kk + 2][rb] = v0.z; Bs[kk + 3][rb] = v0.w;
      Bs[kk + 4][rb] = v1.x; Bs[kk + 5][rb] = v1.y; Bs[kk + 6][rb] = v1.z; Bs[kk + 7][rb] = v1.w;
      Bs[kk + 8][rb] = v2.x; Bs[kk + 9][rb] = v2.y; Bs[kk +10][rb] = v2.z; Bs[kk +11][rb] = v2.w;
      Bs[kk +12][rb] = v3.x; Bs[kk +13][rb] = v3.y; Bs[kk +14][rb] = v3.z; Bs[kk +15][rb] = v3.w;
    }
    __syncthreads();
    for (int k = 0; k < 32; ++k) {
      float4 av = *(const float4*)&As[k][mm * 4];
      float4 b0 = *(const float4*)&Bs[k][nn * 4];
      float4 b1 = *(const float4*)&Bs[k][64 + nn * 4];
      float am[4] = {av.x, av.y, av.z, av.w};
      float bv[2][4] = {{b0.x, b0.y, b0.z, b0.w}, {b1.x, b1.y, b1.z, b1.w}};
      #pragma unroll
      for (int i = 0; i < 4; ++i)
        #pragma unroll
        for (int q = 0; q < 2; ++q)
          #pragma unroll
          for (int j2 = 0; j2 < 4; ++j2)
            acc[q][i][j2] += am[i] * bv[q][j2];
    }
    __syncthreads();
  }
  #pragma unroll
  for (int q = 0; q < 2; ++q) {
    int nc = n0 + q * 64 + nn * 4;
    float4 bv = *(const float4*)(bias + nc);
    #pragma unroll
    for (int i = 0; i < 4; ++i) {
      int row = m0 + mm * 4 + i;
      float4 o;
      o.x = acc[q][i][0] + bv.x;
      o.y = acc[q][i][1] + bv.y;
      o.z = acc[q][i][2] + bv.z;
      o.w = acc[q][i][3] + bv.w;
      *(float4*)(xgslot + (size_t)row * 1024 + nc) = o;
    }
  }
}

// ---------------- persistent LSTM chunk v2: Whh register-resident.
// grid (16 bc, 8 js, 2 dir) = 256 blocks, 1/CU (launch_bounds(256,1) -> big
// VGPR budget, no spill). Block = 32 j x 4 gates x 16 batches.
// Thread (j = tid>>3, ks = tid&7): owns W[4 gates][k-slice ks*32..+32] in
// 32 float4 regs loaded ONCE per chunk (kills per-step L2 W traffic, the
// round-3 bottleneck). h via LDS with +8-floats-per-32 swizzle (16B-aligned,
// 2-way bank alias = free). k-partials: 3-level shfl_xor butterfly over ks.
// Cell update: thread handles batches b0=bc*16+ks*2 (+0,+1); acc picked via
// static-index cndmask tree (no dynamic reg indexing).
__global__ __launch_bounds__(256, 1) void lstm_chunk(
    const float* __restrict__ xgf, const float* __restrict__ xgb,
    const float* __restrict__ whf, const float* __restrict__ whb,
    const int* __restrict__ blen,
    float* __restrict__ hst, float* __restrict__ cst,
    float* __restrict__ hout, unsigned* __restrict__ bar,
    int s0, int nsteps) {
  const int bc = blockIdx.x, js = blockIdx.y, dir = blockIdx.z;
  const int tid = threadIdx.x;
  const int j = tid >> 3;            // 0..31
  const int ks = tid & 7;            // k-slice, lane bits 0-2 (shfl_xor 1,2,4)
  const int jg = js * 32 + j;
  const int colj = jg + ((jg >> 5) << 3);   // swizzled LDS col for k=jg
  const int grp = dir * 16 + bc;
  const float* wh = dir ? whb : whf;
  const float* xgp = dir ? xgb : xgf;

  __shared__ float h_lds[16 * 320];  // [b_local][col], 320 = 256 + 8 pads of 8

  // ---- W into registers: 4 gate-rows x 8 float4 (k = ks*32 .. +32)
  float4 wr[4][8];
  #pragma unroll
  for (int g = 0; g < 4; ++g)
    #pragma unroll
    for (int q = 0; q < 8; ++q)
      wr[g][q] = *(const float4*)(wh + ((size_t)(g * 256 + jg)) * 256 +
                                  ks * 32 + q * 4);

  const int b0 = bc * 16 + ks * 2;   // this thread's 2 batch rows
  const int len0 = blen[b0];
  const int len1 = blen[b0 + 1];
  float c0 = cst[((size_t)dir * 256 + b0) * 256 + jg];
  float c1 = cst[((size_t)dir * 256 + b0 + 1) * 256 + jg];

  for (int r = 0; r < nsteps; ++r) {
    const int s = s0 + r;
    const int tt = dir ? (199 - s) : s;
    const int rslot = s & 1, wslot = 1 - rslot;

    // ---- stage h[16 b][256 k] from LLC (agent scope; producers on other XCDs)
    const float* hsrc = hst + (((size_t)(rslot * 2 + dir)) * 256 + bc * 16) * 256;
    #pragma unroll
    for (int p = 0; p < 16; ++p) {
      int i = tid + p * 256;
      int b = i >> 8, k = i & 255;
      float v = __hip_atomic_load(hsrc + b * 256 + k, __ATOMIC_RELAXED,
                                  __HIP_MEMORY_SCOPE_AGENT);
      h_lds[b * 320 + k + ((k >> 5) << 3)] = v;
    }
    __syncthreads();

    // ---- xg loads issued early; consumed after the GEMM (hidden in its shadow)
    float xq[4][2];
    #pragma unroll
    for (int g = 0; g < 4; ++g)
      #pragma unroll
      for (int u = 0; u < 2; ++u)
        xq[g][u] = xgp[((size_t)r * 256 + b0 + u) * 1024 + g * 256 + jg];

    // ---- GEMM: acc[g][b] = sum over this thread's 32 k of W*h
    float acc[4][16];
    #pragma unroll
    for (int g = 0; g < 4; ++g)
      #pragma unroll
      for (int b = 0; b < 16; ++b) acc[g][b] = 0.f;

    #pragma unroll
    for (int q = 0; q < 8; ++q) {
      const int col = ks * 40 + q * 4;   // k + ((k>>5)<<3), k = ks*32+q*4
      #pragma unroll
      for (int b = 0; b < 16; ++b) {
        float4 h4 = *(const float4*)&h_lds[b * 320 + col];
        #pragma unroll
        for (int g = 0; g < 4; ++g)
          acc[g][b] += wr[g][q].x * h4.x + wr[g][q].y * h4.y +
                       wr[g][q].z * h4.z + wr[g][q].w * h4.w;
      }
    }

    // ---- butterfly reduce over ks (lane bits 0-2): all 8 lanes -> full sums
    #pragma unroll
    for (int g = 0; g < 4; ++g)
      #pragma unroll
      for (int b = 0; b < 16; ++b) {
        float v = acc[g][b];
        v += __shfl_xor(v, 1);
        v += __shfl_xor(v, 2);
        v += __shfl_xor(v, 4);
        acc[g][b] = v;
      }

    // ---- cell update for b = ks*2 + u (static-index select tree over ks bits)
    #pragma unroll
    for (int u = 0; u < 2; ++u) {
      float ga[4];
      #pragma unroll
      for (int g = 0; g < 4; ++g) {
        float p0 = (ks & 1) ? acc[g][2 + u]  : acc[g][0 + u];
        float p1 = (ks & 1) ? acc[g][6 + u]  : acc[g][4 + u];
        float p2 = (ks & 1) ? acc[g][10 + u] : acc[g][8 + u];
        float p3 = (ks & 1) ? acc[g][14 + u] : acc[g][12 + u];
        float q0 = (ks & 2) ? p1 : p0;
        float q1 = (ks & 2) ? p3 : p2;
        ga[g] = (ks & 4) ? q1 : q0;
      }
      float gi = 1.f / (1.f + expf(-(ga[0] + xq[0][u])));
      float gf = 1.f / (1.f + expf(-(ga[1] + xq[1][u])));
      float gg = tanhf(ga[2] + xq[2][u]);
      float go = 1.f / (1.f + expf(-(ga[3] + xq[3][u])));
      float c_old = u ? c1 : c0;
      float cn = gf * c_old + gi * gg;
      float hn = go * tanhf(cn);
      const int bg = b0 + u;
      const bool mk = tt < (u ? len1 : len0);
      if (mk) { if (u) c1 = cn; else c0 = cn; }
      float hold = h_lds[(ks * 2 + u) * 320 + colj];
      float hsv = mk ? hn : hold;
      __hip_atomic_store(
          hst + (((size_t)(wslot * 2 + dir)) * 256 + bg) * 256 + jg,
          hsv, __ATOMIC_RELAXED, __HIP_MEMORY_SCOPE_AGENT);
      hout[(((size_t)dir * 200 + tt) * 256 + bg) * 256 + jg] = mk ? hn : 0.f;
    }

    // ---- group barrier (8 js-blocks of (dir,bc))
    asm volatile("s_waitcnt vmcnt(0)" ::: "memory");  // drain agent h stores
    __syncthreads();
    if (tid == 0) {
      __hip_atomic_fetch_add(&bar[grp * 32], 1u, __ATOMIC_RELAXED,
                             __HIP_MEMORY_SCOPE_AGENT);
      const unsigned tgt = 8u * (unsigned)(s + 1);
      while (__hip_atomic_load(&bar[grp * 32], __ATOMIC_RELAXED,
                               __HIP_MEMORY_SCOPE_AGENT) < tgt) {}
    }
    __syncthreads();
  }

  // persist c for next chunk launch (kernel boundary flushes)
  cst[((size_t)dir * 256 + b0) * 256 + jg] = c0;
  cst[((size_t)dir * 256 + b0 + 1) * 256 + jg] = c1;
}

// ---------------- feats[b][t][k] = [hf|hb] . W_tag[k] + b_tag[k]
__global__ __launch_bounds__(256) void feats_kernel(
    const float* __restrict__ h_out, const float* __restrict__ wtag,
    const float* __restrict__ btag, float* __restrict__ feats) {
  __shared__ float hcat[32][512];
  const int t = blockIdx.x, bc = blockIdx.y;
  const int tid = threadIdx.x;
  const float* hf = h_out + (((size_t)0 * 200 + t) * 256 + bc * 32) * 256;
  const float* hb = h_out + (((size_t)1 * 200 + t) * 256 + bc * 32) * 256;
  for (int i = tid; i < 2048; i += 256) {
    int row = i >> 6, c4 = (i & 63) << 2;
    *(float4*)&hcat[row][c4] = *(const float4*)(hf + (size_t)row * 256 + c4);
    *(float4*)&hcat[row][256 + c4] = *(const float4*)(hb + (size_t)row * 256 + c4);
  }
  __syncthreads();
  const int kk = tid & 63;
  const int bg = tid >> 6;
  if (kk < 52) {
    float acc[8];
    #pragma unroll
    for (int i = 0; i < 8; ++i) acc[i] = 0.f;
    const float* wr = wtag + (size_t)kk * 512;
    for (int jq = 0; jq < 128; ++jq) {
      float4 wv = *(const float4*)(wr + jq * 4);
      #pragma unroll
      for (int bi = 0; bi < 8; ++bi) {
        float4 hv = *(const float4*)&hcat[bg * 8 + bi][jq * 4];
        acc[bi] += wv.x * hv.x + wv.y * hv.y + wv.z * hv.z + wv.w * hv.w;
      }
    }
    float bv = btag[kk];
    #pragma unroll
    for (int bi = 0; bi < 8; ++bi)
      feats[(size_t)(bc * 32 + bg * 8 + bi) * 10400 + t * 52 + kk] = acc[bi] + bv;
  }
}

// ---------------- Viterbi: one WG per batch row; bp kept in LDS; np semantics.
__global__ __launch_bounds__(256) void viterbi_kernel(
    const float* __restrict__ feats, const float* __restrict__ trans,
    const int* __restrict__ blen, float* __restrict__ out) {
  const int b = blockIdx.x;
  const int tid = threadIdx.x;
  const int k = tid & 63;
  const int g = tid >> 6;
  __shared__ float trl[52 * 52];
  __shared__ float part[52];
  __shared__ float redv[4][64];
  __shared__ int redi[4][64];
  __shared__ int bp[199][52];
  __shared__ float finals[64];

  for (int i = tid; i < 2704; i += 256) trl[i] = trans[i];
  const float* fb = feats + (size_t)b * 10400;
  const int len = blen[b];
  __syncthreads();
  if (tid < 52) part[tid] = trl[50 * 52 + tid] + fb[tid];   // START row = 50
  __syncthreads();

  for (int t = 1; t < 200; ++t) {
    float mv = -1e30f;
    int mj = 0;
    if (k < 52) {
      const float ftk = fb[t * 52 + k];
      #pragma unroll
      for (int jj = 0; jj < 13; ++jj) {
        const int jdx = g * 13 + jj;
        float cand = (part[jdx] + trl[jdx * 52 + k]) + ftk;  // np eval order
        if (cand > mv) { mv = cand; mj = jdx; }              // first-index ties
      }
    }
    redv[g][k] = mv;
    redi[g][k] = mj;
    __syncthreads();
    if (g == 0 && k < 52) {
      float bv = redv[0][k]; int bj = redi[0][k];
      #pragma unroll
      for (int u = 1; u < 4; ++u)
        if (redv[u][k] > bv) { bv = redv[u][k]; bj = redi[u][k]; }
      bool m = t < len;
      bp[t - 1][k] = m ? bj : k;     // ident when masked
      if (m) part[k] = bv;
    }
    __syncthreads();
  }

  if (g == 0 && k < 52) finals[k] = part[k] + trl[k * 52 + 51];  // STOP col = 51
  __syncthreads();
  if (tid == 0) {
    float bs = finals[0]; int bt = 0;
    for (int kk2 = 1; kk2 < 52; ++kk2)
      if (finals[kk2] > bs) { bs = finals[kk2]; bt = kk2; }
    out[b] = bs;
    int tag = bt;
    float* dec = out + 256 + (size_t)b * 200;
    dec[199] = (199 < len) ? (float)tag : 0.f;
    for (int i = 198; i >= 0; --i) {
      tag = bp[i][tag];
      dec[i] = (i < len) ? (float)tag : 0.f;
    }
  }
}

extern "C" void kernel_launch(void* const* d_in, const int* in_sizes, int n_in,
                              void* d_out, int out_size, void* d_ws, size_t ws_size,
                              hipStream_t stream) {
  const int*   bin  = (const int*)d_in[0];
  const int*   bfe  = (const int*)d_in[1];
  const int*   blen = (const int*)d_in[2];
  // d_in[3] batch_recover: unused. d_in[4] mask: derived from batch_len.
  const float* ctab = (const float*)d_in[5];
  const float* ftab = (const float*)d_in[6];
  const float* wihf = (const float*)d_in[7];
  const float* whhf = (const float*)d_in[8];
  const float* bf   = (const float*)d_in[9];
  const float* wihb = (const float*)d_in[10];
  const float* whhb = (const float*)d_in[11];
  const float* bb   = (const float*)d_in[12];
  const float* wtag = (const float*)d_in[13];
  const float* btag = (const float*)d_in[14];
  const float* trn  = (const float*)d_in[15];

  // ---- workspace layout (floats), sized to fit ws_size ----
  // fixed: hst 262144 + cst 131072 + hout 26214400 + fts 2662400 + bar 1024
  const size_t FIXED_F = 29271040;
  size_t ws_f = ws_size / sizeof(float);
  int C = 1;
  const int cands[8] = {25, 20, 10, 8, 5, 4, 2, 1};
  for (int u = 0; u < 8; ++u) {
    if (FIXED_F + (size_t)2 * cands[u] * 262144 <= ws_f) { C = cands[u]; break; }
  }

  float* ws  = (float*)d_ws;
  float* xgf = ws;                          // C * 262144
  float* xgb = xgf + (size_t)C * 262144;    // C * 262144
  float* hst = xgb + (size_t)C * 262144;    // 262,144 (2 slots x 2 dir x 256 x 256)
  float* cst = hst + 262144;                // 131,072
  float* hout = cst + 131072;               // 26,214,400 (2 dir x 200 x 256 x 256)
  float* fts  = hout + 26214400;            // 2,662,400
  unsigned* bar = (unsigned*)(fts + 2662400); // 1024 u32 (32 groups x 32 stride)
  float* out  = (float*)d_out;

  hipMemsetAsync(hst, 0, (size_t)(262144 + 131072) * sizeof(float), stream);
  hipMemsetAsync(bar, 0, 1024 * sizeof(unsigned), stream);

  const int nchunks = 200 / C;
  for (int c = 0; c < nchunks; ++c) {
    // forward chunk: local row r holds t = c*C + r
    xg_gemm<<<dim3(4 * C, 8), 256, 0, stream>>>(bin, bfe, ctab, ftab, wihf, bf,
                                                xgf, c * C, 1);
    // backward chunk: local row r holds t = (199 - c*C) - r
    xg_gemm<<<dim3(4 * C, 8), 256, 0, stream>>>(bin, bfe, ctab, ftab, wihb, bb,
                                                xgb, 199 - c * C, -1);
    lstm_chunk<<<dim3(16, 8, 2), 256, 0, stream>>>(xgf, xgb, whhf, whhb, blen,
                                                   hst, cst, hout, bar,
                                                   c * C, C);
  }
  feats_kernel<<<dim3(200, 8), 256, 0, stream>>>(hout, wtag, btag, fts);
  viterbi_kernel<<<256, 256, 0, stream>>>(fts, trn, blen, out);
}

// Round 5
// 3572.931 us; speedup vs baseline: 2.5167x; 2.5167x over previous
//
#include <hip/hip_runtime.h>
#include <math.h>

#define T_ 200
#define WROW 284                       // LDS row stride (256 + swizzle room), 16B-aligned
#define SMEM_FLOATS (128 * WROW + 16 * WROW)
#define SMEM_BYTES (SMEM_FLOATS * 4)   // 163,584 <= 163,840 (160 KiB)

// ---------------- xg GEMM (unchanged from round 2 — proven absmax 0)
__global__ __launch_bounds__(256) void xg_gemm(
    const int* __restrict__ bin, const int* __restrict__ bfe,
    const float* __restrict__ ctab, const float* __restrict__ ftab,
    const float* __restrict__ wih, const float* __restrict__ bias,
    float* __restrict__ xgslot, int t0, int sgn) {
  __shared__ float As[32][68];
  __shared__ float Bs[32][132];
  const int tid = threadIdx.x;
  const int m0 = blockIdx.x * 64;
  const int n0 = blockIdx.y * 128;

  const int mm = tid & 15;
  const int nn = tid >> 4;

  float acc[2][4][4];
  #pragma unroll
  for (int q = 0; q < 2; ++q)
    #pragma unroll
    for (int i = 0; i < 4; ++i)
      #pragma unroll
      for (int j2 = 0; j2 < 4; ++j2) acc[q][i][j2] = 0.f;

  const int ra = tid & 63, ka = tid >> 6;
  const int rb = tid & 127, kb = tid >> 7;

  const int mrow = m0 + ra;
  const int rloc = mrow >> 8;
  const int bcol = mrow & 255;
  const int t = t0 + sgn * rloc;
  const float* cr = ctab + ((size_t)bin[bcol * T_ + t] << 8);
  const float* fr = ftab + ((size_t)bfe[bcol * T_ + t] << 8);

  for (int ks = 0; ks < 256; ks += 32) {
    {
      const float* c0p = cr + ks + ka * 8;
      const float* f0p = fr + ks + ka * 8;
      float4 c0 = *(const float4*)(c0p);
      float4 c1 = *(const float4*)(c0p + 4);
      float4 f0 = *(const float4*)(f0p);
      float4 f1 = *(const float4*)(f0p + 4);
      int kk = ka * 8;
      As[kk + 0][ra] = c0.x * f0.x; As[kk + 1][ra] = c0.y * f0.y;
      As[kk + 2][ra] = c0.z * f0.z; As[kk + 3][ra] = c0.w * f0.w;
      As[kk + 4][ra] = c1.x * f1.x; As[kk + 5][ra] = c1.y * f1.y;
      As[kk + 6][ra] = c1.z * f1.z; As[kk + 7][ra] = c1.w * f1.w;
    }
    {
      const float* src = wih + (size_t)(n0 + rb) * 256 + ks + kb * 16;
      float4 v0 = *(const float4*)(src);
      float4 v1 = *(const float4*)(src + 4);
      float4 v2 = *(const float4*)(src + 8);
      float4 v3 = *(const float4*)(src + 12);
      int kk = kb * 16;
      Bs[kk + 0][rb] = v0.x; Bs[kk + 1][rb] = v0.y; Bs[kk + 2][rb] = v0.z; Bs[kk + 3][rb] = v0.w;
      Bs[kk + 4][rb] = v1.x; Bs[kk + 5][rb] = v1.y; Bs[kk + 6][rb] = v1.z; Bs[kk + 7][rb] = v1.w;
      Bs[kk + 8][rb] = v2.x; Bs[kk + 9][rb] = v2.y; Bs[kk +10][rb] = v2.z; Bs[kk +11][rb] = v2.w;
      Bs[kk +12][rb] = v3.x; Bs[kk +13][rb] = v3.y; Bs[kk +14][rb] = v3.z; Bs[kk +15][rb] = v3.w;
    }
    __syncthreads();
    for (int k = 0; k < 32; ++k) {
      float4 av = *(const float4*)&As[k][mm * 4];
      float4 b0 = *(const float4*)&Bs[k][nn * 4];
      float4 b1 = *(const float4*)&Bs[k][64 + nn * 4];
      float am[4] = {av.x, av.y, av.z, av.w};
      float bv[2][4] = {{b0.x, b0.y, b0.z, b0.w}, {b1.x, b1.y, b1.z, b1.w}};
      #pragma unroll
      for (int i = 0; i < 4; ++i)
        #pragma unroll
        for (int q = 0; q < 2; ++q)
          #pragma unroll
          for (int j2 = 0; j2 < 4; ++j2)
            acc[q][i][j2] += am[i] * bv[q][j2];
    }
    __syncthreads();
  }
  #pragma unroll
  for (int q = 0; q < 2; ++q) {
    int nc = n0 + q * 64 + nn * 4;
    float4 bv = *(const float4*)(bias + nc);
    #pragma unroll
    for (int i = 0; i < 4; ++i) {
      int row = m0 + mm * 4 + i;
      float4 o;
      o.x = acc[q][i][0] + bv.x;
      o.y = acc[q][i][1] + bv.y;
      o.z = acc[q][i][2] + bv.z;
      o.w = acc[q][i][3] + bv.w;
      *(float4*)(xgslot + (size_t)row * 1024 + nc) = o;
    }
  }
}

// ---------------- persistent LSTM chunk v3: Whh slice resident in LDS.
// grid (16 bc, 8 js, 2 dir) = 256 blocks, 1/CU (LDS 163,584 B).
// Block: 128 gate-rows (4 gates x 32 j) x 16 batches. W staged ONCE per chunk,
// rows PERMUTED so thread (rg) reads rows {g*2+u} = its own cell-update gates:
//   prow = rg*8 + g*2 + u  <->  Whh[g*256 + js*32 + rg*2 + u][:]
// Thread (ks = tid&7 k-split of 32k, bg = (tid>>3)&1 batch half, rg = tid>>4):
// GEMM tile 8 rows x 8 batches x 32 k; 3-round pair-halving butterfly over ks
// (live accs 64->32->16->8, no persistent W regs -> no spill).
// In-row LDS swizzle col = k + (k>>5)*4 spreads the 8 ks lanes over banks.
__global__ __launch_bounds__(256, 1) void lstm_chunk(
    const float* __restrict__ xgf, const float* __restrict__ xgb,
    const float* __restrict__ whf, const float* __restrict__ whb,
    const int* __restrict__ blen,
    float* __restrict__ hst, float* __restrict__ cst,
    float* __restrict__ hout, unsigned* __restrict__ bar,
    int s0, int nsteps) {
  extern __shared__ float smem[];
  float* wlds = smem;                 // [128][WROW]
  float* hlds = smem + 128 * WROW;    // [16][WROW]

  const int bc = blockIdx.x, js = blockIdx.y, dir = blockIdx.z;
  const int tid = threadIdx.x;
  const int ks = tid & 7;
  const int bg = (tid >> 3) & 1;
  const int rg = tid >> 4;            // 0..15
  const int grp = dir * 16 + bc;
  const float* wh = dir ? whb : whf;
  const float* xgp = dir ? xgb : xgf;

  // ---- stage W once per chunk (permuted rows, swizzled cols)
  #pragma unroll
  for (int i = 0; i < 32; ++i) {
    int f = tid + i * 256;            // quad id 0..8191
    int prow = f >> 6;
    int k = (f & 63) << 2;
    int g = (prow >> 1) & 3, u = prow & 1, rgs = prow >> 3;
    int jg = js * 32 + rgs * 2 + u;
    float4 v = *(const float4*)(wh + ((size_t)(g * 256 + jg)) * 256 + k);
    *(float4*)&wlds[prow * WROW + k + ((k >> 5) << 2)] = v;
  }

  const int b_th = bc * 16 + bg * 8 + ks;   // this thread's batch row
  const int bl_th = bg * 8 + ks;            // local batch index
  const int jg0 = js * 32 + rg * 2;         // j for u=0
  const int cj0 = jg0 + ((jg0 >> 5) << 2);  // swizzled col of jg0 (u=1 -> +1)
  const int len_th = blen[b_th];
  float c0 = cst[((size_t)dir * 256 + b_th) * 256 + jg0];
  float c1 = cst[((size_t)dir * 256 + b_th) * 256 + jg0 + 1];

  __syncthreads();   // W staged

  for (int r = 0; r < nsteps; ++r) {
    const int s = s0 + r;
    const int tt = dir ? (199 - s) : s;
    const int rslot = s & 1, wslot = 1 - rslot;

    // ---- stage h[16 b][256 k] (agent scope: producers on other XCDs)
    const float* hsrc = hst + (((size_t)(rslot * 2 + dir)) * 256 + bc * 16) * 256;
    #pragma unroll
    for (int p = 0; p < 16; ++p) {
      int i = tid + p * 256;
      int b = i >> 8, k = i & 255;
      float v = __hip_atomic_load(hsrc + b * 256 + k, __ATOMIC_RELAXED,
                                  __HIP_MEMORY_SCOPE_AGENT);
      hlds[b * WROW + k + ((k >> 5) << 2)] = v;
    }
    __syncthreads();

    // ---- xg loads issued early, consumed after GEMM
    float xq[4][2];
    #pragma unroll
    for (int g = 0; g < 4; ++g)
      #pragma unroll
      for (int u = 0; u < 2; ++u)
        xq[g][u] = xgp[((size_t)r * 256 + b_th) * 1024 + g * 256 + jg0 + u];

    // ---- GEMM: acc[i][bb] over this thread's 32-k slice
    float acc[8][8];
    #pragma unroll
    for (int i = 0; i < 8; ++i)
      #pragma unroll
      for (int bb = 0; bb < 8; ++bb) acc[i][bb] = 0.f;

    #pragma unroll
    for (int kq = 0; kq < 8; ++kq) {
      const int col = ks * 36 + kq * 4;   // swizzled col of k = ks*32 + kq*4
      float4 w4[8], h4[8];
      #pragma unroll
      for (int i = 0; i < 8; ++i)
        w4[i] = *(const float4*)&wlds[(rg * 8 + i) * WROW + col];
      #pragma unroll
      for (int bb = 0; bb < 8; ++bb)
        h4[bb] = *(const float4*)&hlds[(bg * 8 + bb) * WROW + col];
      #pragma unroll
      for (int i = 0; i < 8; ++i)
        #pragma unroll
        for (int bb = 0; bb < 8; ++bb)
          acc[i][bb] += w4[i].x * h4[bb].x + w4[i].y * h4[bb].y +
                        w4[i].z * h4[bb].z + w4[i].w * h4[bb].w;
    }

    // ---- pair-halving butterfly over ks (lane bits 0-2): lane ks ends with
    // full sums for batch bl = bg*8 + ks. Live accs 64 -> 32 -> 16 -> 8.
    const int bit0 = ks & 1, bit1 = (ks >> 1) & 1, bit2 = (ks >> 2) & 1;
    float rd1[8][4];
    #pragma unroll
    for (int i = 0; i < 8; ++i)
      #pragma unroll
      for (int m = 0; m < 4; ++m) {
        float keep = bit0 ? acc[i][2 * m + 1] : acc[i][2 * m];
        float send = bit0 ? acc[i][2 * m] : acc[i][2 * m + 1];
        rd1[i][m] = keep + __shfl_xor(send, 1);
      }
    float rd2[8][2];
    #pragma unroll
    for (int i = 0; i < 8; ++i)
      #pragma unroll
      for (int m = 0; m < 2; ++m) {
        float keep = bit1 ? rd1[i][2 * m + 1] : rd1[i][2 * m];
        float send = bit1 ? rd1[i][2 * m] : rd1[i][2 * m + 1];
        rd2[i][m] = keep + __shfl_xor(send, 2);
      }
    float fin[8];
    #pragma unroll
    for (int i = 0; i < 8; ++i) {
      float keep = bit2 ? rd2[i][1] : rd2[i][0];
      float send = bit2 ? rd2[i][0] : rd2[i][1];
      fin[i] = keep + __shfl_xor(send, 4);
    }

    // ---- cell update: j = jg0 + u, b = b_th; fin[g*2+u] are its 4 gates
    #pragma unroll
    for (int u = 0; u < 2; ++u) {
      float gi = 1.f / (1.f + expf(-(fin[0 + u] + xq[0][u])));
      float gf = 1.f / (1.f + expf(-(fin[2 + u] + xq[1][u])));
      float gg = tanhf(fin[4 + u] + xq[2][u]);
      float go = 1.f / (1.f + expf(-(fin[6 + u] + xq[3][u])));
      float c_old = u ? c1 : c0;
      float cn = gf * c_old + gi * gg;
      float hn = go * tanhf(cn);
      const bool mk = tt < len_th;
      if (mk) { if (u) c1 = cn; else c0 = cn; }
      float hold = hlds[bl_th * WROW + cj0 + u];
      float hsv = mk ? hn : hold;
      __hip_atomic_store(
          hst + (((size_t)(wslot * 2 + dir)) * 256 + b_th) * 256 + jg0 + u,
          hsv, __ATOMIC_RELAXED, __HIP_MEMORY_SCOPE_AGENT);
      hout[(((size_t)dir * 200 + tt) * 256 + b_th) * 256 + jg0 + u] =
          mk ? hn : 0.f;
    }

    // ---- group barrier (8 js-blocks of (dir,bc)); mechanism proven in r3/r4
    asm volatile("s_waitcnt vmcnt(0)" ::: "memory");
    __syncthreads();
    if (tid == 0) {
      __hip_atomic_fetch_add(&bar[grp * 32], 1u, __ATOMIC_RELAXED,
                             __HIP_MEMORY_SCOPE_AGENT);
      const unsigned tgt = 8u * (unsigned)(s + 1);
      while (__hip_atomic_load(&bar[grp * 32], __ATOMIC_RELAXED,
                               __HIP_MEMORY_SCOPE_AGENT) < tgt) {}
    }
    __syncthreads();
  }

  // persist c for next chunk launch (kernel boundary flushes)
  cst[((size_t)dir * 256 + b_th) * 256 + jg0] = c0;
  cst[((size_t)dir * 256 + b_th) * 256 + jg0 + 1] = c1;
}

// ---------------- feats[b][t][k] = [hf|hb] . W_tag[k] + b_tag[k]  (r2, proven)
__global__ __launch_bounds__(256) void feats_kernel(
    const float* __restrict__ h_out, const float* __restrict__ wtag,
    const float* __restrict__ btag, float* __restrict__ feats) {
  __shared__ float hcat[32][512];
  const int t = blockIdx.x, bc = blockIdx.y;
  const int tid = threadIdx.x;
  const float* hf = h_out + (((size_t)0 * 200 + t) * 256 + bc * 32) * 256;
  const float* hb = h_out + (((size_t)1 * 200 + t) * 256 + bc * 32) * 256;
  for (int i = tid; i < 2048; i += 256) {
    int row = i >> 6, c4 = (i & 63) << 2;
    *(float4*)&hcat[row][c4] = *(const float4*)(hf + (size_t)row * 256 + c4);
    *(float4*)&hcat[row][256 + c4] = *(const float4*)(hb + (size_t)row * 256 + c4);
  }
  __syncthreads();
  const int kk = tid & 63;
  const int bg = tid >> 6;
  if (kk < 52) {
    float acc[8];
    #pragma unroll
    for (int i = 0; i < 8; ++i) acc[i] = 0.f;
    const float* wr = wtag + (size_t)kk * 512;
    for (int jq = 0; jq < 128; ++jq) {
      float4 wv = *(const float4*)(wr + jq * 4);
      #pragma unroll
      for (int bi = 0; bi < 8; ++bi) {
        float4 hv = *(const float4*)&hcat[bg * 8 + bi][jq * 4];
        acc[bi] += wv.x * hv.x + wv.y * hv.y + wv.z * hv.z + wv.w * hv.w;
      }
    }
    float bv = btag[kk];
    #pragma unroll
    for (int bi = 0; bi < 8; ++bi)
      feats[(size_t)(bc * 32 + bg * 8 + bi) * 10400 + t * 52 + kk] = acc[bi] + bv;
  }
}

// ---------------- Viterbi (r2, proven absmax 0)
__global__ __launch_bounds__(256) void viterbi_kernel(
    const float* __restrict__ feats, const float* __restrict__ trans,
    const int* __restrict__ blen, float* __restrict__ out) {
  const int b = blockIdx.x;
  const int tid = threadIdx.x;
  const int k = tid & 63;
  const int g = tid >> 6;
  __shared__ float trl[52 * 52];
  __shared__ float part[52];
  __shared__ float redv[4][64];
  __shared__ int redi[4][64];
  __shared__ int bp[199][52];
  __shared__ float finals[64];

  for (int i = tid; i < 2704; i += 256) trl[i] = trans[i];
  const float* fb = feats + (size_t)b * 10400;
  const int len = blen[b];
  __syncthreads();
  if (tid < 52) part[tid] = trl[50 * 52 + tid] + fb[tid];
  __syncthreads();

  for (int t = 1; t < 200; ++t) {
    float mv = -1e30f;
    int mj = 0;
    if (k < 52) {
      const float ftk = fb[t * 52 + k];
      #pragma unroll
      for (int jj = 0; jj < 13; ++jj) {
        const int jdx = g * 13 + jj;
        float cand = (part[jdx] + trl[jdx * 52 + k]) + ftk;
        if (cand > mv) { mv = cand; mj = jdx; }
      }
    }
    redv[g][k] = mv;
    redi[g][k] = mj;
    __syncthreads();
    if (g == 0 && k < 52) {
      float bv = redv[0][k]; int bj = redi[0][k];
      #pragma unroll
      for (int u = 1; u < 4; ++u)
        if (redv[u][k] > bv) { bv = redv[u][k]; bj = redi[u][k]; }
      bool m = t < len;
      bp[t - 1][k] = m ? bj : k;
      if (m) part[k] = bv;
    }
    __syncthreads();
  }

  if (g == 0 && k < 52) finals[k] = part[k] + trl[k * 52 + 51];
  __syncthreads();
  if (tid == 0) {
    float bs = finals[0]; int bt = 0;
    for (int kk2 = 1; kk2 < 52; ++kk2)
      if (finals[kk2] > bs) { bs = finals[kk2]; bt = kk2; }
    out[b] = bs;
    int tag = bt;
    float* dec = out + 256 + (size_t)b * 200;
    dec[199] = (199 < len) ? (float)tag : 0.f;
    for (int i = 198; i >= 0; --i) {
      tag = bp[i][tag];
      dec[i] = (i < len) ? (float)tag : 0.f;
    }
  }
}

extern "C" void kernel_launch(void* const* d_in, const int* in_sizes, int n_in,
                              void* d_out, int out_size, void* d_ws, size_t ws_size,
                              hipStream_t stream) {
  const int*   bin  = (const int*)d_in[0];
  const int*   bfe  = (const int*)d_in[1];
  const int*   blen = (const int*)d_in[2];
  const float* ctab = (const float*)d_in[5];
  const float* ftab = (const float*)d_in[6];
  const float* wihf = (const float*)d_in[7];
  const float* whhf = (const float*)d_in[8];
  const float* bf   = (const float*)d_in[9];
  const float* wihb = (const float*)d_in[10];
  const float* whhb = (const float*)d_in[11];
  const float* bb   = (const float*)d_in[12];
  const float* wtag = (const float*)d_in[13];
  const float* btag = (const float*)d_in[14];
  const float* trn  = (const float*)d_in[15];

  // allow >64KB dynamic LDS for lstm_chunk (idempotent; capture-safe)
  (void)hipFuncSetAttribute(reinterpret_cast<const void*>(lstm_chunk),
                            hipFuncAttributeMaxDynamicSharedMemorySize,
                            SMEM_BYTES);

  // ---- workspace layout (floats), sized to fit ws_size ----
  const size_t FIXED_F = 29271040;
  size_t ws_f = ws_size / sizeof(float);
  int C = 1;
  const int cands[8] = {25, 20, 10, 8, 5, 4, 2, 1};
  for (int u = 0; u < 8; ++u) {
    if (FIXED_F + (size_t)2 * cands[u] * 262144 <= ws_f) { C = cands[u]; break; }
  }

  float* ws  = (float*)d_ws;
  float* xgf = ws;
  float* xgb = xgf + (size_t)C * 262144;
  float* hst = xgb + (size_t)C * 262144;    // 2 slots x 2 dir x 256 x 256
  float* cst = hst + 262144;
  float* hout = cst + 131072;               // 2 dir x 200 x 256 x 256
  float* fts  = hout + 26214400;
  unsigned* bar = (unsigned*)(fts + 2662400);
  float* out  = (float*)d_out;

  hipMemsetAsync(hst, 0, (size_t)(262144 + 131072) * sizeof(float), stream);
  hipMemsetAsync(bar, 0, 1024 * sizeof(unsigned), stream);

  const int nchunks = 200 / C;
  for (int c = 0; c < nchunks; ++c) {
    xg_gemm<<<dim3(4 * C, 8), 256, 0, stream>>>(bin, bfe, ctab, ftab, wihf, bf,
                                                xgf, c * C, 1);
    xg_gemm<<<dim3(4 * C, 8), 256, 0, stream>>>(bin, bfe, ctab, ftab, wihb, bb,
                                                xgb, 199 - c * C, -1);
    lstm_chunk<<<dim3(16, 8, 2), 256, SMEM_BYTES, stream>>>(
        xgf, xgb, whhf, whhb, blen, hst, cst, hout, bar, c * C, C);
  }
  feats_kernel<<<dim3(200, 8), 256, 0, stream>>>(hout, wtag, btag, fts);
  viterbi_kernel<<<256, 256, 0, stream>>>(fts, trn, blen, out);
}

// Round 6
// 3248.621 us; speedup vs baseline: 2.7679x; 1.0998x over previous
//
#include <hip/hip_runtime.h>
#include <math.h>

#define T_ 200
#define WROW 284                       // LDS row stride (256 + swizzle room)
#define SMEM_FLOATS (128 * WROW + 16 * WROW)
#define SMEM_BYTES (SMEM_FLOATS * 4)   // 163,584 <= 163,840 (160 KiB)

__device__ __forceinline__ float fsig(float x) {
  return 1.f / (1.f + __expf(-x));
}
__device__ __forceinline__ float ftanh(float x) {
  return 1.f - 2.f / (__expf(2.f * x) + 1.f);   // exact at +-inf, no NaN
}

// ---------------- xg GEMM with fused embedding gather + masked-tile early exit
__global__ __launch_bounds__(256) void xg_gemm(
    const int* __restrict__ bin, const int* __restrict__ bfe,
    const int* __restrict__ blen,
    const float* __restrict__ ctab, const float* __restrict__ ftab,
    const float* __restrict__ wih, const float* __restrict__ bias,
    float* __restrict__ xgslot, int t0, int sgn) {
  const int m0 = blockIdx.x * 64;
  const int rloc = m0 >> 8;
  const int t_blk = t0 + sgn * rloc;
  // tile batches [m0&255, +64); lengths sorted desc -> first is max.
  if (t_blk >= blen[m0 & 255]) return;   // fully masked tile: consumers discard

  __shared__ float As[32][68];
  __shared__ float Bs[32][132];
  const int tid = threadIdx.x;
  const int n0 = blockIdx.y * 128;

  const int mm = tid & 15;
  const int nn = tid >> 4;

  float acc[2][4][4];
  #pragma unroll
  for (int q = 0; q < 2; ++q)
    #pragma unroll
    for (int i = 0; i < 4; ++i)
      #pragma unroll
      for (int j2 = 0; j2 < 4; ++j2) acc[q][i][j2] = 0.f;

  const int ra = tid & 63, ka = tid >> 6;
  const int rb = tid & 127, kb = tid >> 7;

  const int bcol = (m0 + ra) & 255;
  const float* cr = ctab + ((size_t)bin[bcol * T_ + t_blk] << 8);
  const float* fr = ftab + ((size_t)bfe[bcol * T_ + t_blk] << 8);

  for (int ks = 0; ks < 256; ks += 32) {
    {
      const float* c0p = cr + ks + ka * 8;
      const float* f0p = fr + ks + ka * 8;
      float4 c0 = *(const float4*)(c0p);
      float4 c1 = *(const float4*)(c0p + 4);
      float4 f0 = *(const float4*)(f0p);
      float4 f1 = *(const float4*)(f0p + 4);
      int kk = ka * 8;
      As[kk + 0][ra] = c0.x * f0.x; As[kk + 1][ra] = c0.y * f0.y;
      As[kk + 2][ra] = c0.z * f0.z; As[kk + 3][ra] = c0.w * f0.w;
      As[kk + 4][ra] = c1.x * f1.x; As[kk + 5][ra] = c1.y * f1.y;
      As[kk + 6][ra] = c1.z * f1.z; As[kk + 7][ra] = c1.w * f1.w;
    }
    {
      const float* src = wih + (size_t)(n0 + rb) * 256 + ks + kb * 16;
      float4 v0 = *(const float4*)(src);
      float4 v1 = *(const float4*)(src + 4);
      float4 v2 = *(const float4*)(src + 8);
      float4 v3 = *(const float4*)(src + 12);
      int kk = kb * 16;
      Bs[kk + 0][rb] = v0.x; Bs[kk + 1][rb] = v0.y; Bs[kk + 2][rb] = v0.z; Bs[kk + 3][rb] = v0.w;
      Bs[kk + 4][rb] = v1.x; Bs[kk + 5][rb] = v1.y; Bs[kk + 6][rb] = v1.z; Bs[kk + 7][rb] = v1.w;
      Bs[kk + 8][rb] = v2.x; Bs[kk + 9][rb] = v2.y; Bs[kk +10][rb] = v2.z; Bs[kk +11][rb] = v2.w;
      Bs[kk +12][rb] = v3.x; Bs[kk +13][rb] = v3.y; Bs[kk +14][rb] = v3.z; Bs[kk +15][rb] = v3.w;
    }
    __syncthreads();
    for (int k = 0; k < 32; ++k) {
      float4 av = *(const float4*)&As[k][mm * 4];
      float4 b0 = *(const float4*)&Bs[k][nn * 4];
      float4 b1 = *(const float4*)&Bs[k][64 + nn * 4];
      float am[4] = {av.x, av.y, av.z, av.w};
      float bv[2][4] = {{b0.x, b0.y, b0.z, b0.w}, {b1.x, b1.y, b1.z, b1.w}};
      #pragma unroll
      for (int i = 0; i < 4; ++i)
        #pragma unroll
        for (int q = 0; q < 2; ++q)
          #pragma unroll
          for (int j2 = 0; j2 < 4; ++j2)
            acc[q][i][j2] += am[i] * bv[q][j2];
    }
    __syncthreads();
  }
  #pragma unroll
  for (int q = 0; q < 2; ++q) {
    int nc = n0 + q * 64 + nn * 4;
    float4 bv = *(const float4*)(bias + nc);
    #pragma unroll
    for (int i = 0; i < 4; ++i) {
      int row = m0 + mm * 4 + i;
      float4 o;
      o.x = acc[q][i][0] + bv.x;
      o.y = acc[q][i][1] + bv.y;
      o.z = acc[q][i][2] + bv.z;
      o.w = acc[q][i][3] + bv.w;
      *(float4*)(xgslot + (size_t)row * 1024 + nc) = o;
    }
  }
}

// ---------------- persistent LSTM chunk v4: W-in-LDS + 512 threads (2 waves/SIMD).
// grid (16 bc, 8 js, 2 dir) = 256 blocks, 1 block/CU, 8 waves each.
// Thread (ks=tid&7, bg=(tid>>3)&3, rg=tid>>5): GEMM tile 8 rows x 4 batches x 32 k.
// W permuted rows: prow = rgs*8 + g*2 + u <-> Whh[g*256 + js*32 + rgs*2 + u].
// Butterfly over ks: xor1,xor2 split 4 batches -> 1 (batch ks&3), xor4 pure
// k-reduce; lane duplication over ks>>2 picks u (thread's j = js*32+rg*2+(ks>>2)).
__global__ __launch_bounds__(512, 1) void lstm_chunk(
    const float* __restrict__ xgf, const float* __restrict__ xgb,
    const float* __restrict__ whf, const float* __restrict__ whb,
    const int* __restrict__ blen,
    float* __restrict__ hst, float* __restrict__ cst,
    float* __restrict__ hout, unsigned* __restrict__ bar,
    int s0, int nsteps) {
  extern __shared__ float smem[];
  float* wlds = smem;                 // [128][WROW]
  float* hlds = smem + 128 * WROW;    // [16][WROW]

  const int bc = blockIdx.x, js = blockIdx.y, dir = blockIdx.z;
  const int tid = threadIdx.x;
  const int ks = tid & 7;
  const int bg = (tid >> 3) & 3;
  const int rg = tid >> 5;            // 0..15
  const int grp = dir * 16 + bc;
  const float* wh = dir ? whb : whf;
  const float* xgp = dir ? xgb : xgf;

  // ---- stage W once per chunk (permuted rows, swizzled cols)
  #pragma unroll
  for (int i = 0; i < 16; ++i) {
    int f = tid + i * 512;            // float4 id 0..8191
    int prow = f >> 6;
    int k = (f & 63) << 2;
    int g = (prow >> 1) & 3, u = prow & 1, rgs = prow >> 3;
    int jg = js * 32 + rgs * 2 + u;
    float4 v = *(const float4*)(wh + ((size_t)(g * 256 + jg)) * 256 + k);
    *(float4*)&wlds[prow * WROW + k + ((k >> 5) << 2)] = v;
  }

  const int bl_th = bg * 4 + (ks & 3);      // local batch 0..15
  const int b_th = bc * 16 + bl_th;         // global batch
  const int u_th = ks >> 2;
  const int jth = js * 32 + rg * 2 + u_th;  // this thread's j
  const int cjth = jth + ((jth >> 5) << 2); // swizzled col of jth
  const int len_th = blen[b_th];
  float c0 = cst[((size_t)dir * 256 + b_th) * 256 + jth];

  __syncthreads();   // W staged

  for (int r = 0; r < nsteps; ++r) {
    const int s = s0 + r;
    const int tt = dir ? (199 - s) : s;
    const int rslot = s & 1, wslot = 1 - rslot;

    // ---- xg loads first (HBM latency hidden under staging + GEMM)
    float xq[4];
    #pragma unroll
    for (int g = 0; g < 4; ++g)
      xq[g] = xgp[((size_t)r * 256 + b_th) * 1024 + g * 256 + jth];

    // ---- stage h[16 b][256 k] (agent scope: producers on other XCDs)
    const float* hsrc = hst + (((size_t)(rslot * 2 + dir)) * 256 + bc * 16) * 256;
    #pragma unroll
    for (int p = 0; p < 8; ++p) {
      int i = tid + p * 512;
      int b = i >> 8, k = i & 255;
      float v = __hip_atomic_load(hsrc + b * 256 + k, __ATOMIC_RELAXED,
                                  __HIP_MEMORY_SCOPE_AGENT);
      hlds[b * WROW + k + ((k >> 5) << 2)] = v;
    }
    __syncthreads();

    // ---- GEMM: acc[i][bb], i = gate-pair row, bb = batch within quad
    float acc[8][4];
    #pragma unroll
    for (int i = 0; i < 8; ++i)
      #pragma unroll
      for (int bb = 0; bb < 4; ++bb) acc[i][bb] = 0.f;

    #pragma unroll
    for (int kq = 0; kq < 8; ++kq) {
      const int col = ks * 36 + kq * 4;
      float4 h4[4];
      #pragma unroll
      for (int bb = 0; bb < 4; ++bb)
        h4[bb] = *(const float4*)&hlds[(bg * 4 + bb) * WROW + col];
      #pragma unroll
      for (int i = 0; i < 8; ++i) {
        float4 w4 = *(const float4*)&wlds[(rg * 8 + i) * WROW + col];
        #pragma unroll
        for (int bb = 0; bb < 4; ++bb)
          acc[i][bb] += w4.x * h4[bb].x + w4.y * h4[bb].y +
                        w4.z * h4[bb].z + w4.w * h4[bb].w;
      }
    }

    // ---- butterfly over ks: xor1/xor2 route batches, xor4 finishes k-reduce
    const int bit0 = ks & 1, bit1 = (ks >> 1) & 1;
    float fin[8];
    #pragma unroll
    for (int i = 0; i < 8; ++i) {
      float k0 = bit0 ? acc[i][1] : acc[i][0];
      float s0v = bit0 ? acc[i][0] : acc[i][1];
      float k1 = bit0 ? acc[i][3] : acc[i][2];
      float s1v = bit0 ? acc[i][2] : acc[i][3];
      float r0 = k0 + __shfl_xor(s0v, 1);
      float r1 = k1 + __shfl_xor(s1v, 1);
      float k2 = bit1 ? r1 : r0;
      float s2v = bit1 ? r0 : r1;
      float r2 = k2 + __shfl_xor(s2v, 2);
      fin[i] = r2 + __shfl_xor(r2, 4);
    }

    // ---- cell update (1 cell per thread: batch b_th, hidden jth)
    float gav_i = (u_th ? fin[1] : fin[0]) + xq[0];
    float gav_f = (u_th ? fin[3] : fin[2]) + xq[1];
    float gav_g = (u_th ? fin[5] : fin[4]) + xq[2];
    float gav_o = (u_th ? fin[7] : fin[6]) + xq[3];
    float gi = fsig(gav_i);
    float gf = fsig(gav_f);
    float gg = ftanh(gav_g);
    float go = fsig(gav_o);
    float cn = gf * c0 + gi * gg;
    float hn = go * ftanh(cn);
    const bool mk = tt < len_th;
    if (mk) c0 = cn;
    float hold = hlds[bl_th * WROW + cjth];
    float hsv = mk ? hn : hold;
    __hip_atomic_store(
        hst + (((size_t)(wslot * 2 + dir)) * 256 + b_th) * 256 + jth,
        hsv, __ATOMIC_RELAXED, __HIP_MEMORY_SCOPE_AGENT);

    // ---- drain hst store, signal, then hout store overlaps the poll
    asm volatile("s_waitcnt vmcnt(0)" ::: "memory");
    __syncthreads();
    if (tid == 0)
      __hip_atomic_fetch_add(&bar[grp * 32], 1u, __ATOMIC_RELAXED,
                             __HIP_MEMORY_SCOPE_AGENT);
    hout[(((size_t)dir * 200 + tt) * 256 + b_th) * 256 + jth] = mk ? hn : 0.f;
    if (tid == 0) {
      const unsigned tgt = 8u * (unsigned)(s + 1);
      while (__hip_atomic_load(&bar[grp * 32], __ATOMIC_RELAXED,
                               __HIP_MEMORY_SCOPE_AGENT) < tgt) {}
    }
    __syncthreads();
  }

  cst[((size_t)dir * 256 + b_th) * 256 + jth] = c0;
}

// ---------------- feats[b][t][k] = [hf|hb] . W_tag[k] + b_tag[k]  (r2, proven)
__global__ __launch_bounds__(256) void feats_kernel(
    const float* __restrict__ h_out, const float* __restrict__ wtag,
    const float* __restrict__ btag, float* __restrict__ feats) {
  __shared__ float hcat[32][512];
  const int t = blockIdx.x, bc = blockIdx.y;
  const int tid = threadIdx.x;
  const float* hf = h_out + (((size_t)0 * 200 + t) * 256 + bc * 32) * 256;
  const float* hb = h_out + (((size_t)1 * 200 + t) * 256 + bc * 32) * 256;
  for (int i = tid; i < 2048; i += 256) {
    int row = i >> 6, c4 = (i & 63) << 2;
    *(float4*)&hcat[row][c4] = *(const float4*)(hf + (size_t)row * 256 + c4);
    *(float4*)&hcat[row][256 + c4] = *(const float4*)(hb + (size_t)row * 256 + c4);
  }
  __syncthreads();
  const int kk = tid & 63;
  const int bg = tid >> 6;
  if (kk < 52) {
    float acc[8];
    #pragma unroll
    for (int i = 0; i < 8; ++i) acc[i] = 0.f;
    const float* wr = wtag + (size_t)kk * 512;
    for (int jq = 0; jq < 128; ++jq) {
      float4 wv = *(const float4*)(wr + jq * 4);
      #pragma unroll
      for (int bi = 0; bi < 8; ++bi) {
        float4 hv = *(const float4*)&hcat[bg * 8 + bi][jq * 4];
        acc[bi] += wv.x * hv.x + wv.y * hv.y + wv.z * hv.z + wv.w * hv.w;
      }
    }
    float bv = btag[kk];
    #pragma unroll
    for (int bi = 0; bi < 8; ++bi)
      feats[(size_t)(bc * 32 + bg * 8 + bi) * 10400 + t * 52 + kk] = acc[bi] + bv;
  }
}

// ---------------- Viterbi v2: one WAVE per batch row; part in registers
// (broadcast via uniform __shfl), bp as u8 in LDS, no __syncthreads in t-loop.
__global__ __launch_bounds__(256) void viterbi_kernel(
    const float* __restrict__ feats, const float* __restrict__ trans,
    const int* __restrict__ blen, float* __restrict__ out) {
  __shared__ float trl[52 * 52];
  __shared__ unsigned char bp[4][199 * 52];

  const int tid = threadIdx.x;
  const int w = tid >> 6;
  const int lane = tid & 63;
  const int b = blockIdx.x * 4 + w;
  const int kk = (lane < 52) ? lane : 0;

  for (int i = tid; i < 2704; i += 256) trl[i] = trans[i];
  __syncthreads();

  const float* fb = feats + (size_t)b * 10400;
  const int len = blen[b];
  float part = (lane < 52) ? (trl[50 * 52 + lane] + fb[lane]) : -1e30f;

  for (int t = 1; t < 200; ++t) {
    const float ftk = fb[t * 52 + kk];
    float mv = -1e30f;
    int mj = 0;
    #pragma unroll 4
    for (int j = 0; j < 52; ++j) {
      float pj = __shfl(part, j);            // uniform j -> broadcast
      float cand = (pj + trl[j * 52 + kk]) + ftk;   // np eval order
      if (cand > mv) { mv = cand; mj = j; }  // first-index ties
    }
    const bool m = t < len;
    if (lane < 52) {
      bp[w][(t - 1) * 52 + lane] = (unsigned char)(m ? mj : lane);
      if (m) part = mv;
    }
  }

  float fin = (lane < 52) ? (part + trl[lane * 52 + 51]) : -1e30f;
  int bi = lane;
  #pragma unroll
  for (int off = 32; off; off >>= 1) {
    float ov = __shfl_down(fin, off);
    int oi = __shfl_down(bi, off);
    if (ov > fin || (ov == fin && oi < bi)) { fin = ov; bi = oi; }
  }
  if (lane == 0) {
    out[b] = fin;
    int tag = bi;
    float* dec = out + 256 + (size_t)b * 200;
    dec[199] = (199 < len) ? (float)tag : 0.f;
    for (int i = 198; i >= 0; --i) {
      tag = bp[w][i * 52 + tag];
      dec[i] = (i < len) ? (float)tag : 0.f;
    }
  }
}

extern "C" void kernel_launch(void* const* d_in, const int* in_sizes, int n_in,
                              void* d_out, int out_size, void* d_ws, size_t ws_size,
                              hipStream_t stream) {
  const int*   bin  = (const int*)d_in[0];
  const int*   bfe  = (const int*)d_in[1];
  const int*   blen = (const int*)d_in[2];
  const float* ctab = (const float*)d_in[5];
  const float* ftab = (const float*)d_in[6];
  const float* wihf = (const float*)d_in[7];
  const float* whhf = (const float*)d_in[8];
  const float* bf   = (const float*)d_in[9];
  const float* wihb = (const float*)d_in[10];
  const float* whhb = (const float*)d_in[11];
  const float* bb   = (const float*)d_in[12];
  const float* wtag = (const float*)d_in[13];
  const float* btag = (const float*)d_in[14];
  const float* trn  = (const float*)d_in[15];

  (void)hipFuncSetAttribute(reinterpret_cast<const void*>(lstm_chunk),
                            hipFuncAttributeMaxDynamicSharedMemorySize,
                            SMEM_BYTES);

  const size_t FIXED_F = 29271040;
  size_t ws_f = ws_size / sizeof(float);
  int C = 1;
  const int cands[8] = {25, 20, 10, 8, 5, 4, 2, 1};
  for (int u = 0; u < 8; ++u) {
    if (FIXED_F + (size_t)2 * cands[u] * 262144 <= ws_f) { C = cands[u]; break; }
  }

  float* ws  = (float*)d_ws;
  float* xgf = ws;
  float* xgb = xgf + (size_t)C * 262144;
  float* hst = xgb + (size_t)C * 262144;    // 2 slots x 2 dir x 256 x 256
  float* cst = hst + 262144;
  float* hout = cst + 131072;               // 2 dir x 200 x 256 x 256
  float* fts  = hout + 26214400;
  unsigned* bar = (unsigned*)(fts + 2662400);
  float* out  = (float*)d_out;

  hipMemsetAsync(hst, 0, (size_t)(262144 + 131072) * sizeof(float), stream);
  hipMemsetAsync(bar, 0, 1024 * sizeof(unsigned), stream);

  const int nchunks = 200 / C;
  for (int c = 0; c < nchunks; ++c) {
    xg_gemm<<<dim3(4 * C, 8), 256, 0, stream>>>(bin, bfe, blen, ctab, ftab,
                                                wihf, bf, xgf, c * C, 1);
    xg_gemm<<<dim3(4 * C, 8), 256, 0, stream>>>(bin, bfe, blen, ctab, ftab,
                                                wihb, bb, xgb, 199 - c * C, -1);
    lstm_chunk<<<dim3(16, 8, 2), 512, SMEM_BYTES, stream>>>(
        xgf, xgb, whhf, whhb, blen, hst, cst, hout, bar, c * C, C);
  }
  feats_kernel<<<dim3(200, 8), 256, 0, stream>>>(hout, wtag, btag, fts);
  viterbi_kernel<<<64, 256, 0, stream>>>(fts, trn, blen, out);
}